// Round 5
// baseline (640.154 us; speedup 1.0000x reference)
//
// R5: D4_CB is float32 (harness upconverts f16) — decode converts f32->f16.
// Pipeline back to f16 end-to-end (matches reference astype(f16) semantics).
#include <hip/hip_runtime.h>
#include <hip/hip_fp16.h>

typedef _Float16 half8 __attribute__((ext_vector_type(8)));
typedef _Float16 half4v __attribute__((ext_vector_type(4)));
typedef float floatx4 __attribute__((ext_vector_type(4)));

#define K_DIM 4096   // inner dim (d_in)
#define N_DIM 4096   // output features (m)
#define B_ROWS 8192  // batch rows (4*2048)

// ---------------- 1. decode: W[j] = f16(D4_CB[Qidxs[j]]) --------------------
// Codebook is 256 rows x 4 f32 (4 KB, L1-resident). Values exact in f16.
__global__ __launch_bounds__(256) void decode_kernel(
    const int* __restrict__ qidxs, const float4* __restrict__ cb,
    half4v* __restrict__ w) {
  int i = blockIdx.x * 256 + threadIdx.x;  // i in [0, 4096*1024)
  float4 v = cb[qidxs[i]];
  half4v h;
  h.x = (_Float16)v.x;
  h.y = (_Float16)v.y;
  h.z = (_Float16)v.z;
  h.w = (_Float16)v.w;
  w[i] = h;
}

// ---------------- 2. fwht over input rows -> f16 ----------------------------
__global__ __launch_bounds__(256) void fwht_in_kernel(
    const float* __restrict__ x, const float* __restrict__ su,
    _Float16* __restrict__ out) {
  __shared__ float s[4096];
  const int t = threadIdx.x;
  const float4* xv = (const float4*)(x + (size_t)blockIdx.x * 4096);
  const float4* uv = (const float4*)su;
  for (int i = t; i < 1024; i += 256) {
    float4 v = xv[i], u = uv[i];
    s[4 * i + 0] = v.x * u.x;
    s[4 * i + 1] = v.y * u.y;
    s[4 * i + 2] = v.z * u.z;
    s[4 * i + 3] = v.w * u.w;
  }
  __syncthreads();
  for (int h = 1; h < 4096; h <<= 1) {
    for (int j = t; j < 2048; j += 256) {
      int idx = ((j & ~(h - 1)) << 1) | (j & (h - 1));
      float a = s[idx], b = s[idx + h];
      s[idx] = a + b;
      s[idx + h] = a - b;
    }
    __syncthreads();
  }
  // combined scale: (1/sqrt(4096)) * (1/1024) = 2^-16
  const float sc = 1.0f / 65536.0f;
  half4v* ov = (half4v*)(out + (size_t)blockIdx.x * 4096);
  for (int i = t; i < 1024; i += 256) {
    half4v h4;
    h4.x = (_Float16)(s[4 * i + 0] * sc);
    h4.y = (_Float16)(s[4 * i + 1] * sc);
    h4.z = (_Float16)(s[4 * i + 2] * sc);
    h4.w = (_Float16)(s[4 * i + 3] * sc);
    ov[i] = h4;
  }
}

// ---------------- 3. GEMM: Z = Xh @ W^T (both row-major over K) -------------
// m97 structure: 128x128 tile, BK=32, 16x16x32 f16 MFMA, global_load_lds w=16.
// Stores f32 (rounded through f16 to match reference z.astype(f16)).
__global__ __launch_bounds__(256) void gemm_kernel(
    const _Float16* __restrict__ A,   // [8192][4096]
    const _Float16* __restrict__ B,   // [4096][4096]  (W, row-major over K)
    float* __restrict__ C) {          // [8192][4096]
  __shared__ _Float16 sA[128 * 32];
  __shared__ _Float16 sB[128 * 32];
  const int t = threadIdx.x;
  const int lane = t & 63;
  const int wave = t >> 6;
  const int wm = wave >> 1, wn = wave & 1;
  const long bm = blockIdx.x * 128;
  const long bn = blockIdx.y * 128;

  floatx4 acc[4][4];
  for (int i = 0; i < 4; i++)
    for (int j = 0; j < 4; j++) acc[i][j] = floatx4{0.f, 0.f, 0.f, 0.f};

  // staging: thread t loads 8 contiguous f16; tile row = t>>2, col = (t&3)*8
  const int srow = t >> 2;
  const int scol = (t & 3) * 8;
  const _Float16* gA0 = A + (bm + srow) * (long)K_DIM + scol;
  const _Float16* gA1 = A + (bm + 64 + srow) * (long)K_DIM + scol;
  const _Float16* gB0 = B + (bn + srow) * (long)K_DIM + scol;
  const _Float16* gB1 = B + (bn + 64 + srow) * (long)K_DIM + scol;
  _Float16* lA0 = sA + t * 8;
  _Float16* lA1 = sA + 2048 + t * 8;
  _Float16* lB0 = sB + t * 8;
  _Float16* lB1 = sB + 2048 + t * 8;

  const int fm = lane & 15;         // m (or n) within 16x16 frag
  const int fk = (lane >> 4) * 8;   // k start for this quad

  for (int kt = 0; kt < K_DIM; kt += 32) {
    __builtin_amdgcn_global_load_lds(
        (const __attribute__((address_space(1))) void*)(gA0 + kt),
        (__attribute__((address_space(3))) void*)lA0, 16, 0, 0);
    __builtin_amdgcn_global_load_lds(
        (const __attribute__((address_space(1))) void*)(gA1 + kt),
        (__attribute__((address_space(3))) void*)lA1, 16, 0, 0);
    __builtin_amdgcn_global_load_lds(
        (const __attribute__((address_space(1))) void*)(gB0 + kt),
        (__attribute__((address_space(3))) void*)lB0, 16, 0, 0);
    __builtin_amdgcn_global_load_lds(
        (const __attribute__((address_space(1))) void*)(gB1 + kt),
        (__attribute__((address_space(3))) void*)lB1, 16, 0, 0);
    __syncthreads();

    half8 af[4], bf[4];
#pragma unroll
    for (int i = 0; i < 4; i++)
      af[i] = *(const half8*)(sA + (wm * 64 + i * 16 + fm) * 32 + fk);
#pragma unroll
    for (int j = 0; j < 4; j++)
      bf[j] = *(const half8*)(sB + (wn * 64 + j * 16 + fm) * 32 + fk);
#pragma unroll
    for (int i = 0; i < 4; i++)
#pragma unroll
      for (int j = 0; j < 4; j++)
        acc[i][j] = __builtin_amdgcn_mfma_f32_16x16x32_f16(af[i], bf[j],
                                                           acc[i][j], 0, 0, 0);
    __syncthreads();
  }

  // epilogue: C/D layout col=lane&15, row=(lane>>4)*4+reg [m89-verified]
  const int cm = (lane >> 4) * 4;
  const int cn = lane & 15;
#pragma unroll
  for (int i = 0; i < 4; i++) {
#pragma unroll
    for (int j = 0; j < 4; j++) {
      long col = bn + wn * 64 + j * 16 + cn;
#pragma unroll
      for (int r = 0; r < 4; r++) {
        long row = bm + wm * 64 + i * 16 + cm + r;
        // round through f16 to match reference z.astype(f16)
        C[row * (long)N_DIM + col] = (float)(_Float16)acc[i][j][r];
      }
    }
  }
}

// ---------------- 4. fwht over Z rows (IN-PLACE on d_out), scale, *SV -------
__global__ __launch_bounds__(256) void fwht_out_kernel(
    float* __restrict__ z, const float* __restrict__ sv,
    const float* __restrict__ wscale) {
  __shared__ float s[4096];
  const int t = threadIdx.x;
  float4* zv = (float4*)(z + (size_t)blockIdx.x * 4096);
  for (int i = t; i < 1024; i += 256) {
    float4 v = zv[i];
    s[4 * i + 0] = v.x;
    s[4 * i + 1] = v.y;
    s[4 * i + 2] = v.z;
    s[4 * i + 3] = v.w;
  }
  __syncthreads();
  for (int h = 1; h < 4096; h <<= 1) {
    for (int j = t; j < 2048; j += 256) {
      int idx = ((j & ~(h - 1)) << 1) | (j & (h - 1));
      float a = s[idx], b = s[idx + h];
      s[idx] = a + b;
      s[idx + h] = a - b;
    }
    __syncthreads();
  }
  // z32 = zh * (Wscale*1024); fwht scale 1/64  => combined Wscale*16
  const float sc = wscale[0] * 16.0f;
  const float4* svv = (const float4*)sv;
  for (int i = t; i < 1024; i += 256) {
    float4 u = svv[i];
    float4 o;
    o.x = s[4 * i + 0] * sc * u.x;
    o.y = s[4 * i + 1] * sc * u.y;
    o.z = s[4 * i + 2] * sc * u.z;
    o.w = s[4 * i + 3] * sc * u.w;
    zv[i] = o;
  }
}

extern "C" void kernel_launch(void* const* d_in, const int* in_sizes, int n_in,
                              void* d_out, int out_size, void* d_ws, size_t ws_size,
                              hipStream_t stream) {
  const float* input = (const float*)d_in[0];
  const int* qidxs = (const int*)d_in[1];
  const float* su = (const float*)d_in[2];
  const float* sv = (const float*)d_in[3];
  const float* wscale = (const float*)d_in[4];
  const float4* cb = (const float4*)d_in[5];  // 256 x 4 f32 (harness upconverts f16)
  float* out = (float*)d_out;

  // ws layout: W16 [32 MB] | Xh [64 MB]  -> total 96 MB
  if (ws_size < 100663296ull) return;  // fail loudly instead of OOB-crashing
  char* ws = (char*)d_ws;
  _Float16* W16 = (_Float16*)ws;                 // 32 MB f16
  _Float16* Xh = (_Float16*)(ws + 33554432ull);  // 64 MB f16

  decode_kernel<<<(4096 * 1024) / 256, 256, 0, stream>>>(qidxs, cb,
                                                         (half4v*)W16);
  fwht_in_kernel<<<B_ROWS, 256, 0, stream>>>(input, su, Xh);
  gemm_kernel<<<dim3(B_ROWS / 128, N_DIM / 128), 256, 0, stream>>>(Xh, W16, out);
  fwht_out_kernel<<<B_ROWS, 256, 0, stream>>>(out, sv, wscale);
}